// Round 14
// baseline (211.044 us; speedup 1.0000x reference)
//
#include <hip/hip_runtime.h>
#include <hip/hip_bf16.h>

#define B  8
#define NV 4096
#define NE 32768
#define D  128
#define KE2 384   // edge GEMM K after u-fold: De + 2*Dv
#define KN2 256   // node GEMM K after u-fold: Dep + Dv
#define KG 384    // Dep + Dvp + Du

using short8 = __attribute__((ext_vector_type(8))) short;
using f32x4  = __attribute__((ext_vector_type(4))) float;

__device__ inline unsigned short f2bf(float f) {
    unsigned u = __builtin_bit_cast(unsigned, f);
    u += 0x7FFFu + ((u >> 16) & 1u);          // RNE
    return (unsigned short)(u >> 16);
}

// 8x fp32 -> bf16x8 (v_cvt_pk_bf16_f32 pairs)
__device__ inline short8 cvt8(float4 a, float4 b) {
    union { __hip_bfloat162 h[4]; short8 v; } u;
    u.h[0] = __float22bfloat162_rn(make_float2(a.x, a.y));
    u.h[1] = __float22bfloat162_rn(make_float2(a.z, a.w));
    u.h[2] = __float22bfloat162_rn(make_float2(b.x, b.y));
    u.h[3] = __float22bfloat162_rn(make_float2(b.z, b.w));
    return u.v;
}

// ---------------------------------------------------------------------------
// weight prep: WtE[n][k]=bf16(W_edge[k][n]) k<384; WtN[n][k]=bf16(W_node[k][n]) k<256
// ---------------------------------------------------------------------------
__global__ __launch_bounds__(256) void prep_weights(
    const float* __restrict__ We, const float* __restrict__ Wn,
    unsigned short* __restrict__ WtE, unsigned short* __restrict__ WtN)
{
    const int idx = blockIdx.x * 256 + threadIdx.x;       // 0 .. 49151
    {   // edge: 128 x 384
        const int n = idx / KE2, k = idx % KE2;
        WtE[idx] = f2bf(We[(size_t)k * D + n]);
    }
    if (idx < 128 * KN2) {                                 // node: 128 x 256
        const int n = idx >> 8, k = idx & 255;
        WtN[idx] = f2bf(Wn[(size_t)k * D + n]);
    }
}

// ---------------------------------------------------------------------------
// bias fold: bias_e[b][n] = b_e[n] + u[b]@W_e[384:,n] ; bias_n likewise (fp32)
// ---------------------------------------------------------------------------
__global__ __launch_bounds__(128) void bias_kernel(
    const float* __restrict__ gu,
    const float* __restrict__ We, const float* __restrict__ be,
    const float* __restrict__ Wn, const float* __restrict__ bn,
    float* __restrict__ bias_e, float* __restrict__ bias_n)
{
    const int b = blockIdx.x, n = threadIdx.x;
    float se = be[n], sn = bn[n];
    for (int k = 0; k < D; ++k) {
        const float uk = gu[(size_t)b * D + k];
        se += uk * We[(size_t)(KE2 + k) * D + n];
        sn += uk * Wn[(size_t)(KN2 + k) * D + n];
    }
    bias_e[(size_t)b * D + n] = se;
    bias_n[(size_t)b * D + n] = sn;
}

// ---------------------------------------------------------------------------
// CSR build: histogram -> per-batch exclusive scan -> scatter edge ids
// ---------------------------------------------------------------------------
__global__ __launch_bounds__(256) void hist_kernel(
    const int* __restrict__ edge_rs, const int* __restrict__ edge_masks,
    int* __restrict__ cnt)
{
    const int idx = blockIdx.x * 256 + threadIdx.x;       // over B*NE
    if (edge_masks[idx]) {
        const int b = idx >> 15;                          // NE = 2^15
        const int r = edge_rs[2 * idx];                   // receiver
        atomicAdd(cnt + b * NV + r, 1);
    }
}

__global__ __launch_bounds__(1024) void scan_kernel(
    const int* __restrict__ cnt, int* __restrict__ off, int* __restrict__ cur)
{
    const int b = blockIdx.x, t = threadIdx.x;
    __shared__ int part[1024];
    int4 c = *(const int4*)(cnt + b * NV + t * 4);
    const int s0 = c.x, s1 = s0 + c.y, s2 = s1 + c.z, s3 = s2 + c.w;
    part[t] = s3;
    __syncthreads();
    #pragma unroll
    for (int d = 1; d < 1024; d <<= 1) {
        const int v = (t >= d) ? part[t - d] : 0;
        __syncthreads();
        part[t] += v;
        __syncthreads();
    }
    const int base = part[t] - s3;                        // exclusive
    int* o = off + b * (NV + 1) + t * 4;
    o[0] = base; o[1] = base + s0; o[2] = base + s1; o[3] = base + s2;
    int4 cc = { base, base + s0, base + s1, base + s2 };
    *(int4*)(cur + b * NV + t * 4) = cc;
    if (t == 1023) off[b * (NV + 1) + NV] = part[1023];
}

__global__ __launch_bounds__(256) void scatter_kernel(
    const int* __restrict__ edge_rs, const int* __restrict__ edge_masks,
    int* __restrict__ cur, int* __restrict__ elist)
{
    const int idx = blockIdx.x * 256 + threadIdx.x;
    if (edge_masks[idx]) {
        const int b = idx >> 15;
        const int e = idx & (NE - 1);
        const int r = edge_rs[2 * idx];
        const int pos = atomicAdd(cur + b * NV + r, 1);
        elist[b * NE + pos] = e;
    }
}

// ---------------------------------------------------------------------------
// Edge block: 128x128 tile, BK=64. A-ONLY double-buffered LDS (32 KB total)
// -> 4 blocks/CU (32 waves). W B-fragments read directly from the L2-hot
// WtE panel inside the MFMA loop. 512 thr = 8 waves (2 row x 4 col).
// __launch_bounds__(512,4): proven 56-64 VGPR no-spill cap (R9/R13);
// (512,6)/(512,8) cap at 40/32 and spill (R10/R12).
// ---------------------------------------------------------------------------
__global__ __launch_bounds__(512, 4) void edge_kernel(
    const float* __restrict__ nodes,
    const float* __restrict__ edges,
    const int*   __restrict__ edge_rs,
    const unsigned short* __restrict__ WtE,   // (128,384) bf16, n-major
    const float* __restrict__ bias_e,         // (B,128) fp32, u-folded
    float* __restrict__ edges_p,
    float* __restrict__ pe)                   // (B*256*2, 128) partials
{
    __shared__ unsigned short Albuf[2][128 * 64];   // 16 KB each = 32 KB total

    const int tid = threadIdx.x;
    const int b   = blockIdx.y;
    const int e0  = blockIdx.x * 128;

    // staging role: thread -> (srow = tid>>2, sq = tid&3), 16 floats per chunk
    const int srow = tid >> 2;                // 0..127
    const int sq   = tid & 3;                 // k quarter
    const int sX   = (srow & 7) << 3;

    const int2 rs = ((const int2*)edge_rs)[(size_t)b * NE + e0 + srow];
    const float* aseg0 = edges + ((size_t)b * NE + e0 + srow) * D;
    const float* aseg1 = nodes + ((size_t)b * NV + rs.x) * D;
    const float* aseg2 = nodes + ((size_t)b * NV + rs.y) * D;

    // compute role: wave (wr, wc) -> rows [64wr,64wr+64), cols [32wc,32wc+32)
    const int lane = tid & 63;
    const int wv   = tid >> 6;                // 0..7
    const int wr   = wv >> 2, wc = wv & 3;
    const int lc   = lane & 15, lg = lane >> 4;
    const int lX   = (lc & 7) << 3;

    float4 av[2], av2[2];

    auto loadA = [&](int t) {
        const float* seg = (t < 2) ? aseg0 : (t < 4) ? aseg1 : aseg2;
        const float* src = seg + (t & 1) * 64 + sq * 16;
        av[0]  = *(const float4*)(src);
        av[1]  = *(const float4*)(src + 4);
        av2[0] = *(const float4*)(src + 8);
        av2[1] = *(const float4*)(src + 12);
    };
    auto writeStage = [&](int buf) {
        unsigned short* Al = Albuf[buf];
        const int g0 = sq * 16;
        *(short8*)(Al + srow * 64 + ((g0    ) ^ sX)) = cvt8(av[0], av[1]);
        *(short8*)(Al + srow * 64 + ((g0 + 8) ^ sX)) = cvt8(av2[0], av2[1]);
    };

    f32x4 acc[4][2] = {};
    auto compute = [&](int buf, int t) {
        const unsigned short* Al = Albuf[buf];
        #pragma unroll
        for (int ksub = 0; ksub < 2; ++ksub) {
            const int k = ksub * 32 + lg * 8;
            short8 afr[4], bfr[2];
            #pragma unroll
            for (int nt = 0; nt < 2; ++nt)    // W direct from L1/L2 hot panel
                bfr[nt] = *(const short8*)(WtE + (size_t)(wc * 32 + nt * 16 + lc) * KE2
                                               + t * 64 + k);
            #pragma unroll
            for (int mt = 0; mt < 4; ++mt)
                afr[mt] = *(const short8*)(Al + (wr * 64 + mt * 16 + lc) * 64 + (k ^ lX));
            #pragma unroll
            for (int mt = 0; mt < 4; ++mt)
                #pragma unroll
                for (int nt = 0; nt < 2; ++nt)
                    acc[mt][nt] = __builtin_amdgcn_mfma_f32_16x16x32_bf16(
                                      afr[mt], bfr[nt], acc[mt][nt], 0, 0, 0);
        }
    };

    // prologue
    loadA(0); writeStage(0);
    __syncthreads();
    // main 2-phase pipeline over 6 K-chunks
    #pragma unroll
    for (int t = 0; t < 6; ++t) {
        if (t < 5) loadA(t + 1);
        compute(t & 1, t);
        if (t < 5) writeStage((t + 1) & 1);
        __syncthreads();
    }

    // epilogue: bias + relu, store, per-block column partial sums (no atomics)
    #pragma unroll
    for (int nt = 0; nt < 2; ++nt) {
        const int col = wc * 32 + nt * 16 + lc;
        const float bias = bias_e[(size_t)b * D + col];
        float csum = 0.f;
        #pragma unroll
        for (int mt = 0; mt < 4; ++mt)
            #pragma unroll
            for (int r = 0; r < 4; ++r) {
                const int row = wr * 64 + mt * 16 + lg * 4 + r;
                const float v = fmaxf(acc[mt][nt][r] + bias, 0.f);
                edges_p[((size_t)b * NE + e0 + row) * D + col] = v;
                csum += v;
            }
        csum += __shfl_xor(csum, 16);
        csum += __shfl_xor(csum, 32);
        if (lg == 0)
            pe[(((size_t)b * 256 + blockIdx.x) * 2 + wr) * D + col] = csum;
    }
}

// ---------------------------------------------------------------------------
// Node block: BM=64 tile -> grid (NV/64, B) = 512 blocks.
// 256 thr = 4 waves (2x2): wave = 32 rows x 64 cols. K=256: chunks 0,1 = e2v
// CSR gather-sum, chunks 2,3 = nodes. A dbuf 16 KB + W dbuf 32 KB = 48 KB.
// ---------------------------------------------------------------------------
__global__ __launch_bounds__(256, 3) void node_kernel(
    const float* __restrict__ nodes,
    const float* __restrict__ edges_p,
    const int*   __restrict__ off,            // (B, NV+1)
    const int*   __restrict__ elist,          // (B, NE)
    const unsigned short* __restrict__ WtN,   // (128,256) bf16, n-major
    const float* __restrict__ bias_n,         // (B,128) fp32, u-folded
    float* __restrict__ nodes_p,
    float* __restrict__ pn)                   // (B*64*2, 128) partials
{
    __shared__ unsigned short Albuf[2][64 * 64];    // 8 KB each
    __shared__ unsigned short Wlbuf[2][128 * 64];   // 16 KB each

    const int tid = threadIdx.x;
    const int b   = blockIdx.y;
    const int n0  = blockIdx.x * 64;

    // A staging: 64 rows, 4 thr/row, 16 floats each
    const int srowA = tid >> 2;               // 0..63
    const int sqA   = tid & 3;
    const int sXA   = (srowA & 7) << 3;
    // W staging: 128 rows, 2 thr/row, 32 ushorts each
    const int srowW = tid >> 1;               // 0..127
    const int sqW   = tid & 1;
    const int sXW   = (srowW & 7) << 3;

    const int vtx = n0 + srowA;
    const int p0  = off[b * (NV + 1) + vtx];
    const int p1  = off[b * (NV + 1) + vtx + 1];
    const float* nsrc = nodes + ((size_t)b * NV + vtx) * D;

    const int lane = tid & 63;
    const int wv   = tid >> 6;                // 0..3
    const int wr   = wv >> 1, wc = wv & 1;
    const int lc   = lane & 15, lg = lane >> 4;
    const int lX   = (lc & 7) << 3;

    float4 av[2], av2[2];
    short8 wstg[4];

    auto loadA = [&](int t) {
        if (t < 2) {   // e2v: CSR gather-sum, this thread's 16-float k-slice
            float4 s0 = {}, s1 = {}, s2 = {}, s3 = {};
            const int koff = (t & 1) * 64 + sqA * 16;
            for (int p = p0; p < p1; ++p) {
                const int e = elist[b * NE + p];
                const float* src = edges_p + ((size_t)b * NE + e) * D + koff;
                const float4 x0 = *(const float4*)(src);
                const float4 x1 = *(const float4*)(src + 4);
                const float4 x2 = *(const float4*)(src + 8);
                const float4 x3 = *(const float4*)(src + 12);
                s0.x += x0.x; s0.y += x0.y; s0.z += x0.z; s0.w += x0.w;
                s1.x += x1.x; s1.y += x1.y; s1.z += x1.z; s1.w += x1.w;
                s2.x += x2.x; s2.y += x2.y; s2.z += x2.z; s2.w += x2.w;
                s3.x += x3.x; s3.y += x3.y; s3.z += x3.z; s3.w += x3.w;
            }
            av[0] = s0; av[1] = s1; av2[0] = s2; av2[1] = s3;
        } else {       // nodes chunk
            const float* src = nsrc + (t - 2) * 64 + sqA * 16;
            av[0]  = *(const float4*)(src);
            av[1]  = *(const float4*)(src + 4);
            av2[0] = *(const float4*)(src + 8);
            av2[1] = *(const float4*)(src + 12);
        }
    };
    auto loadW = [&](int t) {
        const unsigned short* src = WtN + (size_t)srowW * KN2 + t * 64 + sqW * 32;
        wstg[0] = *(const short8*)(src);
        wstg[1] = *(const short8*)(src + 8);
        wstg[2] = *(const short8*)(src + 16);
        wstg[3] = *(const short8*)(src + 24);
    };
    auto writeStage = [&](int buf) {
        unsigned short* Al = Albuf[buf];
        const int gA = sqA * 16;
        *(short8*)(Al + srowA * 64 + ((gA    ) ^ sXA)) = cvt8(av[0], av[1]);
        *(short8*)(Al + srowA * 64 + ((gA + 8) ^ sXA)) = cvt8(av2[0], av2[1]);
        unsigned short* Wl = Wlbuf[buf];
        const int gW = sqW * 32;
        *(short8*)(Wl + srowW * 64 + ((gW     ) ^ sXW)) = wstg[0];
        *(short8*)(Wl + srowW * 64 + ((gW + 8 ) ^ sXW)) = wstg[1];
        *(short8*)(Wl + srowW * 64 + ((gW + 16) ^ sXW)) = wstg[2];
        *(short8*)(Wl + srowW * 64 + ((gW + 24) ^ sXW)) = wstg[3];
    };

    f32x4 acc[2][4] = {};
    auto compute = [&](int buf) {
        const unsigned short* Al = Albuf[buf];
        const unsigned short* Wl = Wlbuf[buf];
        #pragma unroll
        for (int ksub = 0; ksub < 2; ++ksub) {
            const int k = ksub * 32 + lg * 8;
            short8 afr[2], bfr[4];
            #pragma unroll
            for (int mt = 0; mt < 2; ++mt)
                afr[mt] = *(const short8*)(Al + (wr * 32 + mt * 16 + lc) * 64 + (k ^ lX));
            #pragma unroll
            for (int nt = 0; nt < 4; ++nt)
                bfr[nt] = *(const short8*)(Wl + (wc * 64 + nt * 16 + lc) * 64 + (k ^ lX));
            #pragma unroll
            for (int mt = 0; mt < 2; ++mt)
                #pragma unroll
                for (int nt = 0; nt < 4; ++nt)
                    acc[mt][nt] = __builtin_amdgcn_mfma_f32_16x16x32_bf16(
                                      afr[mt], bfr[nt], acc[mt][nt], 0, 0, 0);
        }
    };

    loadA(0); loadW(0); writeStage(0);
    __syncthreads();
    #pragma unroll
    for (int t = 0; t < 4; ++t) {
        if (t < 3) { loadA(t + 1); loadW(t + 1); }
        compute(t & 1);
        if (t < 3) {
            writeStage((t + 1) & 1);
            __syncthreads();
        }
    }

    #pragma unroll
    for (int nt = 0; nt < 4; ++nt) {
        const int col = wc * 64 + nt * 16 + lc;
        const float bias = bias_n[(size_t)b * D + col];
        float csum = 0.f;
        #pragma unroll
        for (int mt = 0; mt < 2; ++mt)
            #pragma unroll
            for (int r = 0; r < 4; ++r) {
                const int row = wr * 32 + mt * 16 + lg * 4 + r;
                const float v = fmaxf(acc[mt][nt][r] + bias, 0.f);
                nodes_p[((size_t)b * NV + n0 + row) * D + col] = v;
                csum += v;
            }
        csum += __shfl_xor(csum, 16);
        csum += __shfl_xor(csum, 32);
        if (lg == 0)
            pn[(((size_t)b * 64 + blockIdx.x) * 2 + wr) * D + col] = csum;
    }
}

// ---------------------------------------------------------------------------
// Partial reduce: e2u[b] = sum pe[b][0:512], v2u[b] = sum pn[b][0:128]
// ---------------------------------------------------------------------------
__global__ __launch_bounds__(256) void reduce_kernel(
    const float* __restrict__ pe, const float* __restrict__ pn,
    float* __restrict__ e2u, float* __restrict__ v2u)
{
    __shared__ float redE[2][128], redN[2][128];
    const int b = blockIdx.x;
    const int j = threadIdx.x & 127;
    const int h = threadIdx.x >> 7;           // 0 or 1
    float s = 0.f;
    for (int i = h * 256; i < h * 256 + 256; ++i)
        s += pe[((size_t)b * 512 + i) * D + j];
    float t = 0.f;
    for (int i = h * 64; i < h * 64 + 64; ++i)
        t += pn[((size_t)b * 128 + i) * D + j];
    redE[h][j] = s;
    redN[h][j] = t;
    __syncthreads();
    if (h == 0) {
        e2u[(size_t)b * D + j] = redE[0][j] + redE[1][j];
        v2u[(size_t)b * D + j] = redN[0][j] + redN[1][j];
    }
}

// ---------------------------------------------------------------------------
// Global block: relu(concat(e2u, v2u, u) @ W_g + b_g)  (fp32, tiny)
// ---------------------------------------------------------------------------
__global__ __launch_bounds__(128) void glob_kernel(
    const float* __restrict__ e2u,
    const float* __restrict__ v2u,
    const float* __restrict__ gu,
    const float* __restrict__ W_glob,
    const float* __restrict__ b_glob,
    float* __restrict__ glob_p)
{
    __shared__ float gin[KG];
    const int b = blockIdx.x;
    const int j = threadIdx.x;

    gin[j      ] = e2u[(size_t)b * D + j];
    gin[j + 128] = v2u[(size_t)b * D + j];
    gin[j + 256] = gu [(size_t)b * D + j];
    __syncthreads();

    float acc = b_glob[j];
    #pragma unroll 4
    for (int k = 0; k < KG; ++k)
        acc += gin[k] * W_glob[(size_t)k * D + j];
    glob_p[(size_t)b * D + j] = fmaxf(acc, 0.f);
}

// ---------------------------------------------------------------------------
extern "C" void kernel_launch(void* const* d_in, const int* in_sizes, int n_in,
                              void* d_out, int out_size, void* d_ws, size_t ws_size,
                              hipStream_t stream) {
    const float* nodes      = (const float*)d_in[0];
    const float* edges      = (const float*)d_in[1];
    const float* gu         = (const float*)d_in[2];
    const int*   edge_rs    = (const int*)d_in[3];
    const int*   edge_masks = (const int*)d_in[4];
    const float* W_edge     = (const float*)d_in[5];
    const float* b_edge     = (const float*)d_in[6];
    const float* W_node     = (const float*)d_in[7];
    const float* b_node     = (const float*)d_in[8];
    const float* W_glob     = (const float*)d_in[9];
    const float* b_glob     = (const float*)d_in[10];

    float* out     = (float*)d_out;
    float* nodes_p = out;
    float* edges_p = out + (size_t)B * NV * D;
    float* glob_p  = edges_p + (size_t)B * NE * D;

    // workspace layout
    int*   cnt    = (int*)d_ws;                        // B*NV
    int*   off    = cnt + (size_t)B * NV;              // B*(NV+1)
    int*   cur    = off + (size_t)B * (NV + 1);        // B*NV
    int*   elist  = cur + (size_t)B * NV;              // B*NE
    float* e2u    = (float*)(elist + (size_t)B * NE);  // B*D
    float* v2u    = e2u + (size_t)B * D;               // B*D
    float* bias_e = v2u + (size_t)B * D;               // B*D
    float* bias_n = bias_e + (size_t)B * D;            // B*D
    float* pe     = bias_n + (size_t)B * D;            // B*512*D
    float* pn     = pe + (size_t)B * 512 * D;          // B*128*D
    unsigned short* WtE = (unsigned short*)(pn + (size_t)B * 128 * D); // 128*384
    unsigned short* WtN = WtE + 128 * KE2;                             // 128*256

    hipMemsetAsync(cnt, 0, (size_t)B * NV * sizeof(int), stream);

    prep_weights<<<(128 * KE2) / 256, 256, 0, stream>>>(W_edge, W_node, WtE, WtN);
    bias_kernel<<<B, 128, 0, stream>>>(gu, W_edge, b_edge, W_node, b_node, bias_e, bias_n);
    hist_kernel<<<(B * NE) / 256, 256, 0, stream>>>(edge_rs, edge_masks, cnt);
    scan_kernel<<<B, 1024, 0, stream>>>(cnt, off, cur);
    scatter_kernel<<<(B * NE) / 256, 256, 0, stream>>>(edge_rs, edge_masks, cur, elist);

    dim3 eg(NE / 128, B);
    edge_kernel<<<eg, 512, 0, stream>>>(nodes, edges, edge_rs,
                                        WtE, bias_e, edges_p, pe);
    dim3 ng(NV / 64, B);
    node_kernel<<<ng, 256, 0, stream>>>(nodes, edges_p, off, elist,
                                        WtN, bias_n, nodes_p, pn);
    reduce_kernel<<<B, 256, 0, stream>>>(pe, pn, e2u, v2u);
    glob_kernel<<<B, 128, 0, stream>>>(e2u, v2u, gu, W_glob, b_glob, glob_p);
}

// Round 15
// 190.248 us; speedup vs baseline: 1.1093x; 1.1093x over previous
//
#include <hip/hip_runtime.h>
#include <hip/hip_bf16.h>

#define B  8
#define NV 4096
#define NE 32768
#define D  128
#define KE2 384   // edge GEMM K after u-fold: De + 2*Dv
#define KN2 256   // node GEMM K after u-fold: Dep + Dv
#define KG 384    // Dep + Dvp + Du

using short8 = __attribute__((ext_vector_type(8))) short;
using f32x4  = __attribute__((ext_vector_type(4))) float;

__device__ inline unsigned short f2bf(float f) {
    unsigned u = __builtin_bit_cast(unsigned, f);
    u += 0x7FFFu + ((u >> 16) & 1u);          // RNE
    return (unsigned short)(u >> 16);
}

// 8x fp32 -> bf16x8 (v_cvt_pk_bf16_f32 pairs)
__device__ inline short8 cvt8(float4 a, float4 b) {
    union { __hip_bfloat162 h[4]; short8 v; } u;
    u.h[0] = __float22bfloat162_rn(make_float2(a.x, a.y));
    u.h[1] = __float22bfloat162_rn(make_float2(a.z, a.w));
    u.h[2] = __float22bfloat162_rn(make_float2(b.x, b.y));
    u.h[3] = __float22bfloat162_rn(make_float2(b.z, b.w));
    return u.v;
}

// ---------------------------------------------------------------------------
// weight prep: WtE[n][k]=bf16(W_edge[k][n]) k<384; WtN[n][k]=bf16(W_node[k][n]) k<256
// ---------------------------------------------------------------------------
__global__ __launch_bounds__(256) void prep_weights(
    const float* __restrict__ We, const float* __restrict__ Wn,
    unsigned short* __restrict__ WtE, unsigned short* __restrict__ WtN)
{
    const int idx = blockIdx.x * 256 + threadIdx.x;       // 0 .. 49151
    {   // edge: 128 x 384
        const int n = idx / KE2, k = idx % KE2;
        WtE[idx] = f2bf(We[(size_t)k * D + n]);
    }
    if (idx < 128 * KN2) {                                 // node: 128 x 256
        const int n = idx >> 8, k = idx & 255;
        WtN[idx] = f2bf(Wn[(size_t)k * D + n]);
    }
}

// ---------------------------------------------------------------------------
// bias fold: bias_e[b][n] = b_e[n] + u[b]@W_e[384:,n] ; bias_n likewise (fp32)
// ---------------------------------------------------------------------------
__global__ __launch_bounds__(128) void bias_kernel(
    const float* __restrict__ gu,
    const float* __restrict__ We, const float* __restrict__ be,
    const float* __restrict__ Wn, const float* __restrict__ bn,
    float* __restrict__ bias_e, float* __restrict__ bias_n)
{
    const int b = blockIdx.x, n = threadIdx.x;
    float se = be[n], sn = bn[n];
    for (int k = 0; k < D; ++k) {
        const float uk = gu[(size_t)b * D + k];
        se += uk * We[(size_t)(KE2 + k) * D + n];
        sn += uk * Wn[(size_t)(KN2 + k) * D + n];
    }
    bias_e[(size_t)b * D + n] = se;
    bias_n[(size_t)b * D + n] = sn;
}

// ---------------------------------------------------------------------------
// CSR build: histogram -> per-batch exclusive scan -> scatter edge ids
// ---------------------------------------------------------------------------
__global__ __launch_bounds__(256) void hist_kernel(
    const int* __restrict__ edge_rs, const int* __restrict__ edge_masks,
    int* __restrict__ cnt)
{
    const int idx = blockIdx.x * 256 + threadIdx.x;       // over B*NE
    if (edge_masks[idx]) {
        const int b = idx >> 15;                          // NE = 2^15
        const int r = edge_rs[2 * idx];                   // receiver
        atomicAdd(cnt + b * NV + r, 1);
    }
}

__global__ __launch_bounds__(1024) void scan_kernel(
    const int* __restrict__ cnt, int* __restrict__ off, int* __restrict__ cur)
{
    const int b = blockIdx.x, t = threadIdx.x;
    __shared__ int part[1024];
    int4 c = *(const int4*)(cnt + b * NV + t * 4);
    const int s0 = c.x, s1 = s0 + c.y, s2 = s1 + c.z, s3 = s2 + c.w;
    part[t] = s3;
    __syncthreads();
    #pragma unroll
    for (int d = 1; d < 1024; d <<= 1) {
        const int v = (t >= d) ? part[t - d] : 0;
        __syncthreads();
        part[t] += v;
        __syncthreads();
    }
    const int base = part[t] - s3;                        // exclusive
    int* o = off + b * (NV + 1) + t * 4;
    o[0] = base; o[1] = base + s0; o[2] = base + s1; o[3] = base + s2;
    int4 cc = { base, base + s0, base + s1, base + s2 };
    *(int4*)(cur + b * NV + t * 4) = cc;
    if (t == 1023) off[b * (NV + 1) + NV] = part[1023];
}

__global__ __launch_bounds__(256) void scatter_kernel(
    const int* __restrict__ edge_rs, const int* __restrict__ edge_masks,
    int* __restrict__ cur, int* __restrict__ elist)
{
    const int idx = blockIdx.x * 256 + threadIdx.x;
    if (edge_masks[idx]) {
        const int b = idx >> 15;
        const int e = idx & (NE - 1);
        const int r = edge_rs[2 * idx];
        const int pos = atomicAdd(cur + b * NV + r, 1);
        elist[b * NE + pos] = e;
    }
}

// ---------------------------------------------------------------------------
// Edge block (R9 structure, XCD batch-pinned): 128x128 tile, BK=64, A+W
// double-buffered LDS (64 KB), 512 thr = 8 waves (2x4), (512,4) -> VGPR 64.
// 1D grid 2048: b = bid&7, tile = bid>>3 -> batch b's blocks all land on
// XCD b under round-robin dispatch; nodes[b] (2 MB) becomes L2-resident.
// ---------------------------------------------------------------------------
__global__ __launch_bounds__(512, 4) void edge_kernel(
    const float* __restrict__ nodes,
    const float* __restrict__ edges,
    const int*   __restrict__ edge_rs,
    const unsigned short* __restrict__ WtE,   // (128,384) bf16, n-major
    const float* __restrict__ bias_e,         // (B,128) fp32, u-folded
    float* __restrict__ edges_p,
    float* __restrict__ pe)                   // (B*256*2, 128) partials
{
    __shared__ unsigned short Albuf[2][128 * 64];   // 16 KB each
    __shared__ unsigned short Wlbuf[2][128 * 64];

    const int tid  = threadIdx.x;
    const int bid  = blockIdx.x;
    const int b    = bid & 7;                 // batch -> XCD pin
    const int tile = bid >> 3;                // 0..255
    const int e0   = tile * 128;

    // staging role
    const int srow = tid >> 2;                // 0..127
    const int sq   = tid & 3;                 // k quarter (16 elems)
    const int sX   = (srow & 7) << 3;

    const int2 rs = ((const int2*)edge_rs)[(size_t)b * NE + e0 + srow];
    const float* aseg0 = edges + ((size_t)b * NE + e0 + srow) * D;
    const float* aseg1 = nodes + ((size_t)b * NV + rs.x) * D;
    const float* aseg2 = nodes + ((size_t)b * NV + rs.y) * D;

    // compute role: wave (wr, wc) -> rows [64wr,64wr+64), cols [32wc,32wc+32)
    const int lane = tid & 63;
    const int wv   = tid >> 6;                // 0..7
    const int wr   = wv >> 2, wc = wv & 3;
    const int lc   = lane & 15, lg = lane >> 4;
    const int lX   = (lc & 7) << 3;

    float4 av[2], av2[2];
    short8 wstg[2];

    auto loadA = [&](int t) {
        const float* seg = (t < 2) ? aseg0 : (t < 4) ? aseg1 : aseg2;
        const float* src = seg + (t & 1) * 64 + sq * 16;
        av[0]  = *(const float4*)(src);
        av[1]  = *(const float4*)(src + 4);
        av2[0] = *(const float4*)(src + 8);
        av2[1] = *(const float4*)(src + 12);
    };
    auto loadW = [&](int t) {
        const unsigned short* src = WtE + (size_t)srow * KE2 + t * 64 + sq * 16;
        wstg[0] = *(const short8*)(src);
        wstg[1] = *(const short8*)(src + 8);
    };
    auto writeStage = [&](int buf) {
        unsigned short* Al = Albuf[buf];
        unsigned short* Wl = Wlbuf[buf];
        const int g0 = sq * 16;
        *(short8*)(Al + srow * 64 + ((g0    ) ^ sX)) = cvt8(av[0], av[1]);
        *(short8*)(Al + srow * 64 + ((g0 + 8) ^ sX)) = cvt8(av2[0], av2[1]);
        *(short8*)(Wl + srow * 64 + ((g0    ) ^ sX)) = wstg[0];
        *(short8*)(Wl + srow * 64 + ((g0 + 8) ^ sX)) = wstg[1];
    };

    f32x4 acc[4][2] = {};
    auto compute = [&](int buf) {
        const unsigned short* Al = Albuf[buf];
        const unsigned short* Wl = Wlbuf[buf];
        #pragma unroll
        for (int ksub = 0; ksub < 2; ++ksub) {
            const int k = ksub * 32 + lg * 8;
            short8 afr[4], bfr[2];
            #pragma unroll
            for (int mt = 0; mt < 4; ++mt)
                afr[mt] = *(const short8*)(Al + (wr * 64 + mt * 16 + lc) * 64 + (k ^ lX));
            #pragma unroll
            for (int nt = 0; nt < 2; ++nt)
                bfr[nt] = *(const short8*)(Wl + (wc * 32 + nt * 16 + lc) * 64 + (k ^ lX));
            #pragma unroll
            for (int mt = 0; mt < 4; ++mt)
                #pragma unroll
                for (int nt = 0; nt < 2; ++nt)
                    acc[mt][nt] = __builtin_amdgcn_mfma_f32_16x16x32_bf16(
                                      afr[mt], bfr[nt], acc[mt][nt], 0, 0, 0);
        }
    };

    // prologue
    loadA(0); loadW(0); writeStage(0);
    __syncthreads();
    // main 2-phase pipeline over 6 K-chunks
    #pragma unroll
    for (int t = 0; t < 6; ++t) {
        if (t < 5) { loadA(t + 1); loadW(t + 1); }
        compute(t & 1);
        if (t < 5) writeStage((t + 1) & 1);
        __syncthreads();
    }

    // epilogue: bias + relu, store, per-block column partial sums (no atomics)
    #pragma unroll
    for (int nt = 0; nt < 2; ++nt) {
        const int col = wc * 32 + nt * 16 + lc;
        const float bias = bias_e[(size_t)b * D + col];
        float csum = 0.f;
        #pragma unroll
        for (int mt = 0; mt < 4; ++mt)
            #pragma unroll
            for (int r = 0; r < 4; ++r) {
                const int row = wr * 64 + mt * 16 + lg * 4 + r;
                const float v = fmaxf(acc[mt][nt][r] + bias, 0.f);
                edges_p[((size_t)b * NE + e0 + row) * D + col] = v;
                csum += v;
            }
        csum += __shfl_xor(csum, 16);
        csum += __shfl_xor(csum, 32);
        if (lg == 0)
            pe[(((size_t)b * 256 + tile) * 2 + wr) * D + col] = csum;
    }
}

// ---------------------------------------------------------------------------
// Node block (R9 structure, XCD batch-pinned): 128-tile, 512 thr, K=256
// (chunks 0,1 = e2v CSR gather-sum; 2,3 = nodes row). A+W dbuf LDS.
// ---------------------------------------------------------------------------
__global__ __launch_bounds__(512, 4) void node_kernel(
    const float* __restrict__ nodes,
    const float* __restrict__ edges_p,
    const int*   __restrict__ off,            // (B, NV+1)
    const int*   __restrict__ elist,          // (B, NE)
    const unsigned short* __restrict__ WtN,   // (128,256) bf16, n-major
    const float* __restrict__ bias_n,         // (B,128) fp32, u-folded
    float* __restrict__ nodes_p,
    float* __restrict__ pn)                   // (B*32*2, 128) partials
{
    __shared__ unsigned short Albuf[2][128 * 64];
    __shared__ unsigned short Wlbuf[2][128 * 64];

    const int tid  = threadIdx.x;
    const int bid  = blockIdx.x;
    const int b    = bid & 7;                 // batch -> XCD pin
    const int tile = bid >> 3;                // 0..31
    const int n0   = tile * 128;

    const int srow = tid >> 2;
    const int sq   = tid & 3;
    const int sX   = (srow & 7) << 3;

    const int vtx = n0 + srow;
    const int p0  = off[b * (NV + 1) + vtx];
    const int p1  = off[b * (NV + 1) + vtx + 1];
    const float* nsrc = nodes + ((size_t)b * NV + vtx) * D;

    const int lane = tid & 63;
    const int wv   = tid >> 6;
    const int wr   = wv >> 2, wc = wv & 3;
    const int lc   = lane & 15, lg = lane >> 4;
    const int lX   = (lc & 7) << 3;

    float4 av[2], av2[2];
    short8 wstg[2];

    auto loadA = [&](int t) {
        if (t < 2) {   // e2v: CSR gather-sum, this thread's 16-float k-slice
            float4 s0 = {}, s1 = {}, s2 = {}, s3 = {};
            const int koff = (t & 1) * 64 + sq * 16;
            for (int p = p0; p < p1; ++p) {
                const int e = elist[b * NE + p];
                const float* src = edges_p + ((size_t)b * NE + e) * D + koff;
                const float4 x0 = *(const float4*)(src);
                const float4 x1 = *(const float4*)(src + 4);
                const float4 x2 = *(const float4*)(src + 8);
                const float4 x3 = *(const float4*)(src + 12);
                s0.x += x0.x; s0.y += x0.y; s0.z += x0.z; s0.w += x0.w;
                s1.x += x1.x; s1.y += x1.y; s1.z += x1.z; s1.w += x1.w;
                s2.x += x2.x; s2.y += x2.y; s2.z += x2.z; s2.w += x2.w;
                s3.x += x3.x; s3.y += x3.y; s3.z += x3.z; s3.w += x3.w;
            }
            av[0] = s0; av[1] = s1; av2[0] = s2; av2[1] = s3;
        } else {       // nodes chunk
            const float* src = nsrc + (t - 2) * 64 + sq * 16;
            av[0]  = *(const float4*)(src);
            av[1]  = *(const float4*)(src + 4);
            av2[0] = *(const float4*)(src + 8);
            av2[1] = *(const float4*)(src + 12);
        }
    };
    auto loadW = [&](int t) {
        const unsigned short* src = WtN + (size_t)srow * KN2 + t * 64 + sq * 16;
        wstg[0] = *(const short8*)(src);
        wstg[1] = *(const short8*)(src + 8);
    };
    auto writeStage = [&](int buf) {
        unsigned short* Al = Albuf[buf];
        unsigned short* Wl = Wlbuf[buf];
        const int g0 = sq * 16;
        *(short8*)(Al + srow * 64 + ((g0    ) ^ sX)) = cvt8(av[0], av[1]);
        *(short8*)(Al + srow * 64 + ((g0 + 8) ^ sX)) = cvt8(av2[0], av2[1]);
        *(short8*)(Wl + srow * 64 + ((g0    ) ^ sX)) = wstg[0];
        *(short8*)(Wl + srow * 64 + ((g0 + 8) ^ sX)) = wstg[1];
    };

    f32x4 acc[4][2] = {};
    auto compute = [&](int buf) {
        const unsigned short* Al = Albuf[buf];
        const unsigned short* Wl = Wlbuf[buf];
        #pragma unroll
        for (int ksub = 0; ksub < 2; ++ksub) {
            const int k = ksub * 32 + lg * 8;
            short8 afr[4], bfr[2];
            #pragma unroll
            for (int mt = 0; mt < 4; ++mt)
                afr[mt] = *(const short8*)(Al + (wr * 64 + mt * 16 + lc) * 64 + (k ^ lX));
            #pragma unroll
            for (int nt = 0; nt < 2; ++nt)
                bfr[nt] = *(const short8*)(Wl + (wc * 32 + nt * 16 + lc) * 64 + (k ^ lX));
            #pragma unroll
            for (int mt = 0; mt < 4; ++mt)
                #pragma unroll
                for (int nt = 0; nt < 2; ++nt)
                    acc[mt][nt] = __builtin_amdgcn_mfma_f32_16x16x32_bf16(
                                      afr[mt], bfr[nt], acc[mt][nt], 0, 0, 0);
        }
    };

    loadA(0); loadW(0); writeStage(0);
    __syncthreads();
    #pragma unroll
    for (int t = 0; t < 4; ++t) {
        if (t < 3) { loadA(t + 1); loadW(t + 1); }
        compute(t & 1);
        if (t < 3) writeStage((t + 1) & 1);
        __syncthreads();
    }

    #pragma unroll
    for (int nt = 0; nt < 2; ++nt) {
        const int col = wc * 32 + nt * 16 + lc;
        const float bias = bias_n[(size_t)b * D + col];
        float csum = 0.f;
        #pragma unroll
        for (int mt = 0; mt < 4; ++mt)
            #pragma unroll
            for (int r = 0; r < 4; ++r) {
                const int row = wr * 64 + mt * 16 + lg * 4 + r;
                const float v = fmaxf(acc[mt][nt][r] + bias, 0.f);
                nodes_p[((size_t)b * NV + n0 + row) * D + col] = v;
                csum += v;
            }
        csum += __shfl_xor(csum, 16);
        csum += __shfl_xor(csum, 32);
        if (lg == 0)
            pn[(((size_t)b * 32 + tile) * 2 + wr) * D + col] = csum;
    }
}

// ---------------------------------------------------------------------------
// Partial reduce: e2u[b] = sum pe[b][0:512], v2u[b] = sum pn[b][0:64]
// ---------------------------------------------------------------------------
__global__ __launch_bounds__(128) void reduce_kernel(
    const float* __restrict__ pe, const float* __restrict__ pn,
    float* __restrict__ e2u, float* __restrict__ v2u)
{
    const int b = blockIdx.x, j = threadIdx.x;
    float s = 0.f;
    for (int i = 0; i < 512; ++i) s += pe[((size_t)b * 512 + i) * D + j];
    e2u[(size_t)b * D + j] = s;
    float t = 0.f;
    for (int i = 0; i < 64; ++i) t += pn[((size_t)b * 64 + i) * D + j];
    v2u[(size_t)b * D + j] = t;
}

// ---------------------------------------------------------------------------
// Global block: relu(concat(e2u, v2u, u) @ W_g + b_g)  (fp32, tiny)
// ---------------------------------------------------------------------------
__global__ __launch_bounds__(128) void glob_kernel(
    const float* __restrict__ e2u,
    const float* __restrict__ v2u,
    const float* __restrict__ gu,
    const float* __restrict__ W_glob,
    const float* __restrict__ b_glob,
    float* __restrict__ glob_p)
{
    __shared__ float gin[KG];
    const int b = blockIdx.x;
    const int j = threadIdx.x;

    gin[j      ] = e2u[(size_t)b * D + j];
    gin[j + 128] = v2u[(size_t)b * D + j];
    gin[j + 256] = gu [(size_t)b * D + j];
    __syncthreads();

    float acc = b_glob[j];
    #pragma unroll 4
    for (int k = 0; k < KG; ++k)
        acc += gin[k] * W_glob[(size_t)k * D + j];
    glob_p[(size_t)b * D + j] = fmaxf(acc, 0.f);
}

// ---------------------------------------------------------------------------
extern "C" void kernel_launch(void* const* d_in, const int* in_sizes, int n_in,
                              void* d_out, int out_size, void* d_ws, size_t ws_size,
                              hipStream_t stream) {
    const float* nodes      = (const float*)d_in[0];
    const float* edges      = (const float*)d_in[1];
    const float* gu         = (const float*)d_in[2];
    const int*   edge_rs    = (const int*)d_in[3];
    const int*   edge_masks = (const int*)d_in[4];
    const float* W_edge     = (const float*)d_in[5];
    const float* b_edge     = (const float*)d_in[6];
    const float* W_node     = (const float*)d_in[7];
    const float* b_node     = (const float*)d_in[8];
    const float* W_glob     = (const float*)d_in[9];
    const float* b_glob     = (const float*)d_in[10];

    float* out     = (float*)d_out;
    float* nodes_p = out;
    float* edges_p = out + (size_t)B * NV * D;
    float* glob_p  = edges_p + (size_t)B * NE * D;

    // workspace layout
    int*   cnt    = (int*)d_ws;                        // B*NV
    int*   off    = cnt + (size_t)B * NV;              // B*(NV+1)
    int*   cur    = off + (size_t)B * (NV + 1);        // B*NV
    int*   elist  = cur + (size_t)B * NV;              // B*NE
    float* e2u    = (float*)(elist + (size_t)B * NE);  // B*D
    float* v2u    = e2u + (size_t)B * D;               // B*D
    float* bias_e = v2u + (size_t)B * D;               // B*D
    float* bias_n = bias_e + (size_t)B * D;            // B*D
    float* pe     = bias_n + (size_t)B * D;            // B*512*D
    float* pn     = pe + (size_t)B * 512 * D;          // B*64*D
    unsigned short* WtE = (unsigned short*)(pn + (size_t)B * 64 * D);  // 128*384
    unsigned short* WtN = WtE + 128 * KE2;                             // 128*256

    hipMemsetAsync(cnt, 0, (size_t)B * NV * sizeof(int), stream);

    prep_weights<<<(128 * KE2) / 256, 256, 0, stream>>>(W_edge, W_node, WtE, WtN);
    bias_kernel<<<B, 128, 0, stream>>>(gu, W_edge, b_edge, W_node, b_node, bias_e, bias_n);
    hist_kernel<<<(B * NE) / 256, 256, 0, stream>>>(edge_rs, edge_masks, cnt);
    scan_kernel<<<B, 1024, 0, stream>>>(cnt, off, cur);
    scatter_kernel<<<(B * NE) / 256, 256, 0, stream>>>(edge_rs, edge_masks, cur, elist);

    // 1D grids, batch = bid & 7 -> XCD pinning under round-robin dispatch
    edge_kernel<<<(NE / 128) * B, 512, 0, stream>>>(nodes, edges, edge_rs,
                                                    WtE, bias_e, edges_p, pe);
    node_kernel<<<(NV / 128) * B, 512, 0, stream>>>(nodes, edges_p, off, elist,
                                                    WtN, bias_n, nodes_p, pn);
    reduce_kernel<<<B, 128, 0, stream>>>(pe, pn, e2u, v2u);
    glob_kernel<<<B, 128, 0, stream>>>(e2u, v2u, gu, W_glob, b_glob, glob_p);
}